// Round 2
// baseline (23681.503 us; speedup 1.0000x reference)
//
#include <hip/hip_runtime.h>
#include <math.h>

#define B 128
#define T 512
#define C 100
#define E 64
#define H 256
#define KDIM (E + H)     // 320
#define G7 (7 * H)       // 1792
#define G8 8             // padded gate count for float4 loads
#define OROW (6 * H)     // 1536
#define TP1 (T + 1)      // 513
#define BS 2             // batches per recurrent block

// ws layout (floats):
//   [0, KDIM*H*G8)          : Wt2 packed weights [k][h][8 gates]  (2.62 MB)
//   [WS_R, WS_R + B*T*E)    : r (averaged mark embeddings) [B][T][E]
//   [WS_DT, WS_DT + B*T)    : dt (inter-event deltas) [B][T]
#define WS_WT 0
#define WS_R  (KDIM * H * G8)
#define WS_DT (WS_R + B * T * E)
// total ws need: (655360 + 4194304 + 65536) * 4 B ~= 19.7 MB

__device__ __forceinline__ float sigm_(float x) { return 1.0f / (1.0f + expf(-x)); }
__device__ __forceinline__ float softplus_(float x) {
    return fmaxf(x, 0.0f) + log1pf(expf(-fabsf(x)));
}

// ---------------------------------------------------------------------------
// Pack W_cell [7H][KDIM] -> Wt2 [KDIM][H][8]: Wt2[k][h][g] = Wcell[g*H+h][k]
// Thread (k,h) writes 8 consecutive floats (32B) -> coalesced stores.
// ---------------------------------------------------------------------------
__global__ void k_pack(const float* __restrict__ Wc, float* __restrict__ Wt2) {
    const int idx = blockIdx.x * 256 + threadIdx.x;  // 0 .. KDIM*H-1
    const int k = idx >> 8;
    const int h = idx & (H - 1);
    float* o = Wt2 + (size_t)idx * G8;
#pragma unroll
    for (int g = 0; g < 7; ++g)
        o[g] = Wc[(size_t)(g * H + h) * KDIM + k];
    o[7] = 0.0f;
}

// ---------------------------------------------------------------------------
// Averaged mark embeddings r[b][t][e] = (marks @ W_emb)/clip(sum,1,inf)
// plus inter-event deltas dt[b][t]. One block per (b,t), 64 threads (e).
// ---------------------------------------------------------------------------
__global__ void k_embed(const float* __restrict__ marks, const float* __restrict__ Wemb,
                        const float* __restrict__ ts, float* __restrict__ r,
                        float* __restrict__ dt) {
    const int bt = blockIdx.x;  // b*T + t
    const int e = threadIdx.x;  // 0..63
    __shared__ float m[C];
    const float* mrow = marks + (size_t)bt * C;
    m[e] = mrow[e];
    if (e + 64 < C) m[e + 64] = mrow[e + 64];
    __syncthreads();
    float s = 0.f, d = 0.f;
#pragma unroll 4
    for (int c = 0; c < C; ++c) {
        const float mv = m[c];
        s += mv;
        d = fmaf(mv, Wemb[c * E + e], d);
    }
    r[(size_t)bt * E + e] = d / fmaxf(s, 1.0f);
    if (e == 0) {
        const int t = bt & (T - 1);
        const float cur = ts[bt];
        dt[bt] = (t == 0) ? cur : (cur - ts[bt - 1]);
    }
}

// ---------------------------------------------------------------------------
// Persistent recurrent kernel. Grid = B/BS blocks, 1024 threads.
// Thread layout: h = tid&255, b = (tid>>8)&1, gh = tid>>9.
//   gh==0 -> gates {i, f, z, o} for (b,h);  owns state c, c_bar; does update.
//   gh==1 -> gates {i_bar, f_bar, d} for (b,h); prefetches r_{t+1}.
// Weights streamed from L2 as Wt2[k][h][gh*4 .. gh*4+3] -> one dwordx4 per
// (thread, k): wave reads 64 consecutive float4 = 1 KB contiguous.
// ---------------------------------------------------------------------------
__global__ __launch_bounds__(1024) void k_recur(
    const float* __restrict__ Wt2, const float* __restrict__ r,
    const float* __restrict__ dt, const float* __restrict__ bcell,
    const float* __restrict__ init, float* __restrict__ out) {
    __shared__ float feed[BS][KDIM];    // [b][0:E)=r_t, [E:KDIM)=h_d
    __shared__ float gbuf[BS][H][3];    // gib, gfb, gd from gh==1

    const int tid = threadIdx.x;
    const int h = tid & (H - 1);
    const int b = (tid >> 8) & (BS - 1);
    const int gh = tid >> 9;
    const int bg = blockIdx.x * BS + b;

    float c = 0.f, cb = 0.f;
    float B0 = 0.f, B1 = 0.f, B2 = 0.f, B3 = 0.f;
    if (gh == 0) {
        B0 = bcell[0 * H + h]; B1 = bcell[1 * H + h];
        B2 = bcell[2 * H + h]; B3 = bcell[3 * H + h];
    } else {
        B0 = bcell[4 * H + h]; B1 = bcell[5 * H + h]; B2 = bcell[6 * H + h];
    }

    // ---- prologue: initial state + row 0 of output + first feed ----
    if (gh == 0) {
        const float hd0 = tanhf(init[0 * H + h]);
        const float cd0 = tanhf(init[1 * H + h]);
        const float cb0 = tanhf(init[2 * H + h]);
        const float c0  = tanhf(init[3 * H + h]);
        const float d0  = softplus_(init[4 * H + h]);
        const float o0  = sigm_(init[5 * H + h]);
        c = c0; cb = cb0;
        feed[b][E + h] = hd0;
        float* o = out + (size_t)bg * TP1 * OROW;  // row 0
        o[0 * H + h] = hd0; o[1 * H + h] = o0;  o[2 * H + h] = cb0;
        o[3 * H + h] = c0;  o[4 * H + h] = d0;  o[5 * H + h] = cd0;
    } else {
        const int q = tid - H * BS;  // 0..511 within the gh==1 group
        if (q < BS * E) {
            const int bb = q >> 6, e = q & 63;
            feed[bb][e] = r[((size_t)(blockIdx.x * BS + bb) * T + 0) * E + e];
        }
    }
    __syncthreads();

    // per-(thread,k) weight pointer: 4 gates of group gh at slot h
    const float* wbase = Wt2 + (size_t)h * G8 + gh * 4;

    for (int t = 0; t < T; ++t) {
        float a0 = 0.f, a1 = 0.f, a2 = 0.f, a3 = 0.f;
        const float* w = wbase;
        const float* f = feed[b];
#pragma unroll 8
        for (int k = 0; k < KDIM; ++k) {
            const float4 wv = *reinterpret_cast<const float4*>(w);
            const float fv = f[k];
            a0 = fmaf(fv, wv.x, a0);
            a1 = fmaf(fv, wv.y, a1);
            a2 = fmaf(fv, wv.z, a2);
            a3 = fmaf(fv, wv.w, a3);
            w += H * G8;
        }
        if (gh == 1) {
            gbuf[b][h][0] = sigm_(a0 + B0);       // gib
            gbuf[b][h][1] = sigm_(a1 + B1);       // gfb
            gbuf[b][h][2] = softplus_(a2 + B2);   // gd
        }
        __syncthreads();  // gbuf ready; all k-loop reads of feed done

        if (gh == 0) {
            const float gi = sigm_(a0 + B0), gf = sigm_(a1 + B1);
            const float gz = tanhf(a2 + B2), go = sigm_(a3 + B3);
            const float gib = gbuf[b][h][0];
            const float gfb = gbuf[b][h][1];
            const float gd  = gbuf[b][h][2];
            const float dtv = dt[(size_t)bg * T + t];
            const float ct  = gf * c + gi * gz;
            const float cbt = gfb * cb + gib * gz;
            const float cdt = cbt + (ct - cbt) * expf(-gd * dtv);
            const float hdt = go * tanhf(cdt);
            c = ct; cb = cbt;
            feed[b][E + h] = hdt;
            float* o = out + ((size_t)bg * TP1 + (t + 1)) * OROW;
            o[0 * H + h] = hdt; o[1 * H + h] = go;  o[2 * H + h] = cbt;
            o[3 * H + h] = ct;  o[4 * H + h] = gd;  o[5 * H + h] = cdt;
        } else if (t + 1 < T) {
            const int q = tid - H * BS;  // 0..511
            if (q < BS * E) {
                const int bb = q >> 6, e = q & 63;
                feed[bb][e] = r[((size_t)(blockIdx.x * BS + bb) * T + (t + 1)) * E + e];
            }
        }
        __syncthreads();  // feed (h_d + r_{t+1}) published for next step
    }
}

// ---------------------------------------------------------------------------
extern "C" void kernel_launch(void* const* d_in, const int* in_sizes, int n_in,
                              void* d_out, int out_size, void* d_ws, size_t ws_size,
                              hipStream_t stream) {
    const float* marks = (const float*)d_in[0];
    const float* ts    = (const float*)d_in[1];
    const float* Wemb  = (const float*)d_in[2];
    const float* Wcell = (const float*)d_in[3];
    const float* bcell = (const float*)d_in[4];
    const float* init  = (const float*)d_in[5];
    float* out = (float*)d_out;
    float* ws  = (float*)d_ws;

    float* Wt2 = ws + WS_WT;
    float* r   = ws + WS_R;
    float* dtb = ws + WS_DT;

    k_pack<<<KDIM, 256, 0, stream>>>(Wcell, Wt2);
    k_embed<<<B * T, 64, 0, stream>>>(marks, Wemb, ts, r, dtb);
    k_recur<<<B / BS, 1024, 0, stream>>>(Wt2, r, dtb, bcell, init, out);
}

// Round 3
// 11407.838 us; speedup vs baseline: 2.0759x; 2.0759x over previous
//
#include <hip/hip_runtime.h>
#include <math.h>

#define B_ 128
#define T_ 512
#define C_ 100
#define E_ 64
#define H_ 256
#define KDIM 320         // E + H
#define OROW 1536        // 6H
#define TP1 513
#define NCHAIN 8         // independent batch chains
#define NSLICE 32        // h-slices per chain
#define NB 16            // batches per chain
#define HS 8             // h per slice
#define NROW 56          // 7 gates * HS rows per block
#define FP 336           // feed row pitch (floats), 320 + pad
#define GP 65            // gact row pitch (bank-spread)

// ws float offsets
#define WS_R   0                         // r [B][T][E]
#define WS_DT  (B_ * T_ * E_)            // dt [B][T]
#define WS_HD  (WS_DT + B_ * T_)         // hd [2][B][H]  (double-buffered h_d exchange)
#define WS_CNT (WS_HD + 2 * B_ * H_)     // 8 chain counters, 64 floats apart
// total ~17.3 MB of ws

__device__ __forceinline__ float sigm_(float x) { return 1.0f / (1.0f + expf(-x)); }
__device__ __forceinline__ float softplus_(float x) {
    return fmaxf(x, 0.0f) + log1pf(expf(-fabsf(x)));
}

// ---------------------------------------------------------------------------
// Averaged mark embeddings r[b][t][e] + inter-event deltas dt[b][t].
// ---------------------------------------------------------------------------
__global__ void k_embed(const float* __restrict__ marks, const float* __restrict__ Wemb,
                        const float* __restrict__ ts, float* __restrict__ r,
                        float* __restrict__ dt) {
    const int bt = blockIdx.x;
    const int e = threadIdx.x;
    __shared__ float m[C_];
    const float* mrow = marks + (size_t)bt * C_;
    m[e] = mrow[e];
    if (e + 64 < C_) m[e + 64] = mrow[e + 64];
    __syncthreads();
    float s = 0.f, d = 0.f;
#pragma unroll 4
    for (int c = 0; c < C_; ++c) {
        const float mv = m[c];
        s += mv;
        d = fmaf(mv, Wemb[c * E_ + e], d);
    }
    r[(size_t)bt * E_ + e] = d / fmaxf(s, 1.0f);
    if (e == 0) {
        const int t = bt & (T_ - 1);
        const float cur = ts[bt];
        dt[bt] = (t == 0) ? cur : (cur - ts[bt - 1]);
    }
}

// ---------------------------------------------------------------------------
// Cooperative-style recurrent kernel. Grid = 256 blocks, 1024 threads.
//   chain = blockIdx & 7  (16 batches)   slice = blockIdx >> 3 (8 h's)
// Weights for the block's 56 gate rows live in REGISTERS (20 floats/lane,
// kc-16-way K split). Per step: dot+shfl-reduce -> gact LDS -> 128 state
// threads update (b,h) -> h_d to global (agent-scope) -> chain barrier ->
// gather next feed. feed double-buffered in LDS.
// ---------------------------------------------------------------------------
__global__ __launch_bounds__(1024, 4) void k_recur(
    const float* __restrict__ Wcell, const float* __restrict__ bcell,
    const float* __restrict__ init, const float* __restrict__ r,
    const float* __restrict__ dt, float* __restrict__ hd,
    unsigned int* __restrict__ cnt, float* __restrict__ out) {
    __shared__ float feed[2][NB * FP];
    __shared__ float gact[NB * GP];

    const int tid = threadIdx.x;
    const int chain = blockIdx.x & (NCHAIN - 1);
    const int slice = blockIdx.x >> 3;
    const int b0 = chain * NB;
    const int h0 = slice * HS;

    const int wv = tid >> 6;     // wave 0..15
    const int lane = tid & 63;
    const int rl = lane >> 4;    // row-in-wave 0..3
    const int kc = lane & 15;    // K chunk
    const int rr = wv * 4 + rl;  // gate row 0..55 (for wv<14)
    const bool cw = (wv < 14);   // compute wave

    unsigned int* cnt_c = cnt + chain * 64;

    // ---- load weight slice into registers ----
    float W[20];
    if (cw) {
        const int g = rr >> 3, hl = rr & 7;
        const float* src = Wcell + (size_t)(g * H_ + h0 + hl) * KDIM + kc * 20;
#pragma unroll
        for (int j = 0; j < 5; ++j) {
            const float4 v = reinterpret_cast<const float4*>(src)[j];
            W[4 * j + 0] = v.x; W[4 * j + 1] = v.y;
            W[4 * j + 2] = v.z; W[4 * j + 3] = v.w;
        }
    }

    // ---- prologue: state init, biases, row-0 output, feed[0] ----
    float c = 0.f, cb = 0.f, dtv = 0.f;
    float Bb0 = 0, Bb1 = 0, Bb2 = 0, Bb3 = 0, Bb4 = 0, Bb5 = 0, Bb6 = 0;
    if (tid < 128) {
        const int bs = tid >> 3, hl = tid & 7, h = h0 + hl;
        Bb0 = bcell[0 * H_ + h]; Bb1 = bcell[1 * H_ + h]; Bb2 = bcell[2 * H_ + h];
        Bb3 = bcell[3 * H_ + h]; Bb4 = bcell[4 * H_ + h]; Bb5 = bcell[5 * H_ + h];
        Bb6 = bcell[6 * H_ + h];
        const float hd0 = tanhf(init[0 * H_ + h]);
        const float cd0 = tanhf(init[1 * H_ + h]);
        const float cb0 = tanhf(init[2 * H_ + h]);
        const float c0  = tanhf(init[3 * H_ + h]);
        const float d0  = softplus_(init[4 * H_ + h]);
        const float o0  = sigm_(init[5 * H_ + h]);
        c = c0; cb = cb0;
        float* o = out + (size_t)(b0 + bs) * TP1 * OROW + h;
        o[0] = hd0; o[H_] = o0; o[2 * H_] = cb0;
        o[3 * H_] = c0; o[4 * H_] = d0; o[5 * H_] = cd0;
        dtv = dt[(size_t)(b0 + bs) * T_];  // prefetch t=0
        // feed[0] r-part
        const int e8 = hl * 8;
        const float* srcr = r + ((size_t)(b0 + bs) * T_) * E_ + e8;
        reinterpret_cast<float4*>(&feed[0][bs * FP + e8])[0] =
            reinterpret_cast<const float4*>(srcr)[0];
        reinterpret_cast<float4*>(&feed[0][bs * FP + e8])[1] =
            reinterpret_cast<const float4*>(srcr)[1];
    }
    {   // feed[0] h-part: h_d0 = tanh(init[h]) computed locally by every block
        const int flat = tid * 4, bb = flat >> 8, col = flat & 255;
        float4 hv;
        hv.x = tanhf(init[col + 0]); hv.y = tanhf(init[col + 1]);
        hv.z = tanhf(init[col + 2]); hv.w = tanhf(init[col + 3]);
        *reinterpret_cast<float4*>(&feed[0][bb * FP + 64 + col]) = hv;
    }
    __syncthreads();

    // ---- main loop ----
    for (int t = 0; t < T_; ++t) {
        const int p = t & 1;
        // phase A: gate pre-activations (compute waves); r prefetch (helpers)
        if (cw) {
#pragma unroll 2
            for (int b = 0; b < NB; ++b) {
                const float* fb = &feed[p][b * FP + kc * 20];
                float ax = 0.f, ay = 0.f, az = 0.f, aw = 0.f;
#pragma unroll
                for (int j = 0; j < 5; ++j) {
                    const float4 f4 = reinterpret_cast<const float4*>(fb)[j];
                    ax = fmaf(f4.x, W[4 * j + 0], ax);
                    ay = fmaf(f4.y, W[4 * j + 1], ay);
                    az = fmaf(f4.z, W[4 * j + 2], az);
                    aw = fmaf(f4.w, W[4 * j + 3], aw);
                }
                float acc = (ax + ay) + (az + aw);
#pragma unroll
                for (int off = 1; off < 16; off <<= 1)
                    acc += __shfl_xor(acc, off, 16);
                if (kc == 0) gact[b * GP + rr] = acc;
            }
        } else {
            const int q = tid - 896;  // 0..127
            if (t + 1 < T_) {
                const int bb = q >> 3, e8 = (q & 7) * 8;
                const float* src = r + ((size_t)(b0 + bb) * T_ + (t + 1)) * E_ + e8;
                const float4 v0 = reinterpret_cast<const float4*>(src)[0];
                const float4 v1 = reinterpret_cast<const float4*>(src)[1];
                float* dst = &feed[p ^ 1][bb * FP + e8];
                reinterpret_cast<float4*>(dst)[0] = v0;
                reinterpret_cast<float4*>(dst)[1] = v1;
            }
        }
        __syncthreads();

        // phase B: state update for this block's (b, h) pairs
        if (tid < 128) {
            const int bs = tid >> 3, hl = tid & 7;
            const float gi  = sigm_(gact[bs * GP + 0 * 8 + hl] + Bb0);
            const float gf  = sigm_(gact[bs * GP + 1 * 8 + hl] + Bb1);
            const float gz  = tanhf(gact[bs * GP + 2 * 8 + hl] + Bb2);
            const float go  = sigm_(gact[bs * GP + 3 * 8 + hl] + Bb3);
            const float gib = sigm_(gact[bs * GP + 4 * 8 + hl] + Bb4);
            const float gfb = sigm_(gact[bs * GP + 5 * 8 + hl] + Bb5);
            const float gd  = softplus_(gact[bs * GP + 6 * 8 + hl] + Bb6);
            const float ct  = gf * c + gi * gz;
            const float cbt = gfb * cb + gib * gz;
            const float cdt = cbt + (ct - cbt) * expf(-gd * dtv);
            const float hdt = go * tanhf(cdt);
            c = ct; cb = cbt;
            __hip_atomic_store(&hd[p * B_ * H_ + (size_t)(b0 + bs) * H_ + h0 + hl],
                               hdt, __ATOMIC_RELAXED, __HIP_MEMORY_SCOPE_AGENT);
            float* o = out + ((size_t)(b0 + bs) * TP1 + (t + 1)) * OROW + h0 + hl;
            o[0] = hdt; o[H_] = go; o[2 * H_] = cbt;
            o[3 * H_] = ct; o[4 * H_] = gd; o[5 * H_] = cdt;
            if (t + 1 < T_) dtv = dt[(size_t)(b0 + bs) * T_ + t + 1];  // prefetch
        }
        __syncthreads();  // all h_d stores issued & drained (vmcnt0 at barrier)

        // chain barrier: 32 blocks, monotonic counter
        if (tid == 0) {
            __threadfence();
            atomicAdd(cnt_c, 1u);
            const unsigned int tgt = 32u * (unsigned)(t + 1);
            while (__hip_atomic_load(cnt_c, __ATOMIC_RELAXED,
                                     __HIP_MEMORY_SCOPE_AGENT) < tgt)
                __builtin_amdgcn_s_sleep(2);
            __threadfence();
        }
        __syncthreads();

        // phase D: gather full h_d vector for t+1 into feed[p^1]
        {
            const int flat = tid * 4, bb = flat >> 8, col = flat & 255;
            const float* s = hd + p * B_ * H_ + (size_t)(b0 + bb) * H_ + col;
            const float v0 = __hip_atomic_load(s + 0, __ATOMIC_RELAXED, __HIP_MEMORY_SCOPE_AGENT);
            const float v1 = __hip_atomic_load(s + 1, __ATOMIC_RELAXED, __HIP_MEMORY_SCOPE_AGENT);
            const float v2 = __hip_atomic_load(s + 2, __ATOMIC_RELAXED, __HIP_MEMORY_SCOPE_AGENT);
            const float v3 = __hip_atomic_load(s + 3, __ATOMIC_RELAXED, __HIP_MEMORY_SCOPE_AGENT);
            float* dst = &feed[p ^ 1][bb * FP + 64 + col];
            dst[0] = v0; dst[1] = v1; dst[2] = v2; dst[3] = v3;
        }
        __syncthreads();
    }
}

// ---------------------------------------------------------------------------
extern "C" void kernel_launch(void* const* d_in, const int* in_sizes, int n_in,
                              void* d_out, int out_size, void* d_ws, size_t ws_size,
                              hipStream_t stream) {
    const float* marks = (const float*)d_in[0];
    const float* ts    = (const float*)d_in[1];
    const float* Wemb  = (const float*)d_in[2];
    const float* Wcell = (const float*)d_in[3];
    const float* bcell = (const float*)d_in[4];
    const float* init  = (const float*)d_in[5];
    float* out = (float*)d_out;
    float* ws  = (float*)d_ws;

    float* r   = ws + WS_R;
    float* dtb = ws + WS_DT;
    float* hd  = ws + WS_HD;
    unsigned int* cnt = (unsigned int*)(ws + WS_CNT);

    // ws is re-poisoned 0xAA before every timed launch: zero the barrier counters
    hipMemsetAsync(cnt, 0, NCHAIN * 64 * sizeof(unsigned int), stream);
    k_embed<<<B_ * T_, 64, 0, stream>>>(marks, Wemb, ts, r, dtb);
    k_recur<<<NCHAIN * NSLICE, 1024, 0, stream>>>(Wcell, bcell, init, r, dtb, hd, cnt, out);
}